// Round 2
// baseline (188.057 us; speedup 1.0000x reference)
//
#include <hip/hip_runtime.h>
#include <hip/hip_bf16.h>

using bf16 = __hip_bfloat16;
typedef __attribute__((ext_vector_type(8))) short short8;   // 8 bf16 = 4 VGPRs
typedef __attribute__((ext_vector_type(4))) float floatx4;  // 4 fp32 acc
typedef __attribute__((ext_vector_type(8))) int int8v;      // 32 fp8 = 8 VGPRs

__device__ __forceinline__ void async_ld16(const void* g, void* l) {
  __builtin_amdgcn_global_load_lds((const __attribute__((address_space(1))) void*)g,
                                   (__attribute__((address_space(3))) void*)l, 16, 0, 0);
}

__device__ __forceinline__ int pk4_fp8(float a, float b, float c, float d) {
  int v = __builtin_amdgcn_cvt_pk_fp8_f32(a, b, 0, false);
  return __builtin_amdgcn_cvt_pk_fp8_f32(c, d, v, true);  // bytes [a,b,c,d]
}

__device__ __forceinline__ int8v ld_frag16(const unsigned char* lo, const unsigned char* hi) {
  int4 l0 = *(const int4*)lo, h0 = *(const int4*)hi;
  int8v v;
  v[0] = l0.x; v[1] = l0.y; v[2] = l0.z; v[3] = l0.w;
  v[4] = h0.x; v[5] = h0.y; v[6] = h0.z; v[7] = h0.w;
  return v;
}

// Swizzle: chunk j of row r stored at position j ^ (r&7) ^ ((r&8)>>1).
// The r&8 term puts rows fr and fr+8 (same 16-lane read phase) 16 banks apart.

// ---------------- bf16 128x128 tile core (BK=64) — unchanged (0 conflicts) ----------
__device__ __forceinline__ void gemm_core(const bf16* __restrict__ At,
                                          const bf16* __restrict__ Bt,
                                          int K, bf16* lA, bf16* lB,
                                          floatx4 acc[4][4]) {
  const int tid  = threadIdx.x;
  const int w    = tid >> 6;
  const int lane = tid & 63;
  const int subM = (w >> 1) * 64;
  const int subN = (w & 1) * 64;
  const int fr   = lane & 15;
  const int fq   = lane >> 4;

  int srow[4], scol[4], sdst[4];
#pragma unroll
  for (int q = 0; q < 4; ++q) {
    int p = q * 256 + w * 64 + lane;
    int r = p >> 3;
    int j = (p & 7) ^ (r & 7);
    srow[q] = r;
    scol[q] = j * 8;
    sdst[q] = (q * 256 + w * 64) * 8;
  }
  int offA[2][4], offB[2][4];
#pragma unroll
  for (int kc = 0; kc < 2; ++kc)
#pragma unroll
    for (int i = 0; i < 4; ++i) {
      int rA = subM + i * 16 + fr;
      offA[kc][i] = (rA * 8 + ((kc * 4 + fq) ^ (rA & 7))) * 8;
      int rB = subN + i * 16 + fr;
      offB[kc][i] = (rB * 8 + ((kc * 4 + fq) ^ (rB & 7))) * 8;
    }

  floatx4 zero = {0.f, 0.f, 0.f, 0.f};
#pragma unroll
  for (int i = 0; i < 4; ++i)
#pragma unroll
    for (int j = 0; j < 4; ++j) acc[i][j] = zero;

  for (int k0 = 0; k0 < K; k0 += 64) {
    __syncthreads();
#pragma unroll
    for (int q = 0; q < 4; ++q) {
      async_ld16(At + (size_t)srow[q] * K + k0 + scol[q], lA + sdst[q]);
      async_ld16(Bt + (size_t)srow[q] * K + k0 + scol[q], lB + sdst[q]);
    }
    __syncthreads();
#pragma unroll
    for (int kc = 0; kc < 2; ++kc) {
      short8 a[4], b[4];
#pragma unroll
      for (int i = 0; i < 4; ++i) a[i] = *(const short8*)(lA + offA[kc][i]);
#pragma unroll
      for (int j = 0; j < 4; ++j) b[j] = *(const short8*)(lB + offB[kc][j]);
#pragma unroll
      for (int i = 0; i < 4; ++i)
#pragma unroll
        for (int j = 0; j < 4; ++j)
          acc[i][j] = __builtin_amdgcn_mfma_f32_16x16x32_bf16(a[i], b[j], acc[i][j], 0, 0, 0);
    }
  }
}

// ---------------- fp8 128x128 tile core (BK=128) — used by pv ---------------------
__device__ __forceinline__ void gemm_core_f8(const unsigned char* __restrict__ At,
                                             const unsigned char* __restrict__ Bt,
                                             int K, unsigned char* lA, unsigned char* lB,
                                             floatx4 acc[4][4]) {
  const int tid  = threadIdx.x;
  const int w    = tid >> 6;
  const int lane = tid & 63;
  const int subM = (w >> 1) * 64;
  const int subN = (w & 1) * 64;
  const int fr   = lane & 15;
  const int fq   = lane >> 4;

  int srow[4], scol[4], sdst[4];
#pragma unroll
  for (int q = 0; q < 4; ++q) {
    int p = q * 256 + w * 64 + lane;
    int r = p >> 3;
    int j = (p & 7) ^ (r & 7) ^ ((r & 8) >> 1);
    srow[q] = r;
    scol[q] = j * 16;
    sdst[q] = (q * 256 + w * 64) * 16;
  }
  int offA[2][4], offB[2][4];
#pragma unroll
  for (int h = 0; h < 2; ++h)
#pragma unroll
    for (int i = 0; i < 4; ++i) {
      int rA = subM + i * 16 + fr;
      offA[h][i] = rA * 128 + (((fq * 2 + h) ^ (rA & 7) ^ ((rA & 8) >> 1)) * 16);
      int rB = subN + i * 16 + fr;
      offB[h][i] = rB * 128 + (((fq * 2 + h) ^ (rB & 7) ^ ((rB & 8) >> 1)) * 16);
    }

  floatx4 zero = {0.f, 0.f, 0.f, 0.f};
#pragma unroll
  for (int i = 0; i < 4; ++i)
#pragma unroll
    for (int j = 0; j < 4; ++j) acc[i][j] = zero;

  for (int k0 = 0; k0 < K; k0 += 128) {
    __syncthreads();
#pragma unroll
    for (int q = 0; q < 4; ++q) {
      async_ld16(At + (size_t)srow[q] * K + k0 + scol[q], lA + sdst[q]);
      async_ld16(Bt + (size_t)srow[q] * K + k0 + scol[q], lB + sdst[q]);
    }
    __syncthreads();
    int8v a[4], b[4];
#pragma unroll
    for (int i = 0; i < 4; ++i) a[i] = ld_frag16(lA + offA[0][i], lA + offA[1][i]);
#pragma unroll
    for (int j = 0; j < 4; ++j) b[j] = ld_frag16(lB + offB[0][j], lB + offB[1][j]);
#pragma unroll
    for (int i = 0; i < 4; ++i)
#pragma unroll
      for (int j = 0; j < 4; ++j)
        acc[i][j] = __builtin_amdgcn_mfma_scale_f32_16x16x128_f8f6f4(
            a[i], b[j], acc[i][j], 0, 0, 0, 0x7F7F7F7F, 0, 0x7F7F7F7F);
  }
}

// ============ fp8 8-phase core: block 256x256, 8 waves (2Mx4N), BK=128 =============
// Wave tile 128x64: acc[8][4]. LDS 2 x (32KB A + 32KB B) double-buffered = 128KB.
// Per K-tile: 4 phases, each {frag ds_reads | prefetch-issue -> barrier ->
// lgkmcnt(0) -> setprio(1) 8 MFMA setprio(0) -> barrier}. Prefetch for tile t+1
// issued during phases 0-1 of tile t; single vmcnt(0) at tile boundary (loads have
// ~a full tile of compute cover). LDS:MFMA cycle ratio ~0.69 -> MFMA-bound.
__device__ __forceinline__ void gemm_core_f8_8ph(const unsigned char* __restrict__ At,
                                                 const unsigned char* __restrict__ Bt,
                                                 int K, unsigned char* lds0,
                                                 floatx4 acc[8][4]) {
  const int tid  = threadIdx.x;
  const int w    = tid >> 6;
  const int lane = tid & 63;
  const int wr   = w >> 2;
  const int wc   = w & 3;
  const int subM = wr * 128;
  const int subN = wc * 64;
  const int fr   = lane & 15;
  const int fq   = lane >> 4;

  // staging: 2048 16B-chunks per operand tile (256 rows x 8 chunks), 4 per thread
  int srcOff[4], dstOff[4];
#pragma unroll
  for (int q = 0; q < 4; ++q) {
    int p = q * 512 + tid;
    int r = p >> 3;
    int j = (p & 7) ^ (r & 7) ^ ((r & 8) >> 1);
    srcOff[q] = r * K + j * 16;
    dstOff[q] = p * 16;
  }
  int offA[2][8], offB[2][4];
#pragma unroll
  for (int h = 0; h < 2; ++h) {
#pragma unroll
    for (int i = 0; i < 8; ++i) {
      int rA = subM + i * 16 + fr;
      offA[h][i] = rA * 128 + (((fq * 2 + h) ^ (rA & 7) ^ ((rA & 8) >> 1)) * 16);
    }
#pragma unroll
    for (int j = 0; j < 4; ++j) {
      int rB = subN + j * 16 + fr;
      offB[h][j] = rB * 128 + (((fq * 2 + h) ^ (rB & 7) ^ ((rB & 8) >> 1)) * 16);
    }
  }

  auto stageA = [&](int buf, int k0) {
#pragma unroll
    for (int q = 0; q < 4; ++q)
      async_ld16(At + (size_t)(k0 + srcOff[q]), lds0 + buf * 65536 + dstOff[q]);
  };
  auto stageB = [&](int buf, int k0) {
#pragma unroll
    for (int q = 0; q < 4; ++q)
      async_ld16(Bt + (size_t)(k0 + srcOff[q]), lds0 + buf * 65536 + 32768 + dstOff[q]);
  };

  floatx4 zero = {0.f, 0.f, 0.f, 0.f};
#pragma unroll
  for (int i = 0; i < 8; ++i)
#pragma unroll
    for (int j = 0; j < 4; ++j) acc[i][j] = zero;

  // prologue: stage tile 0, full drain once
  stageA(0, 0);
  stageB(0, 0);
  asm volatile("s_waitcnt vmcnt(0)" ::: "memory");
  __builtin_amdgcn_s_barrier();

  const int nt = K >> 7;
  for (int t = 0; t < nt; ++t) {
    const unsigned char* lA = lds0 + (t & 1) * 65536;
    const unsigned char* lB = lA + 32768;
    const int nb = (t + 1) & 1;
    const int k0n = (t + 1) << 7;
    const bool pf = (t + 1) < nt;
    int8v a[4], b0[2], b1[2];

    // ---- phase 0: read A-low frags + B-low frags; prefetch next A ----
#pragma unroll
    for (int i = 0; i < 4; ++i) a[i] = ld_frag16(lA + offA[0][i], lA + offA[1][i]);
#pragma unroll
    for (int j = 0; j < 2; ++j) b0[j] = ld_frag16(lB + offB[0][j], lB + offB[1][j]);
    if (pf) stageA(nb, k0n);
    __builtin_amdgcn_s_barrier();
    asm volatile("s_waitcnt lgkmcnt(0)" ::: "memory");
    __builtin_amdgcn_sched_barrier(0);
    __builtin_amdgcn_s_setprio(1);
#pragma unroll
    for (int i = 0; i < 4; ++i)
#pragma unroll
      for (int j = 0; j < 2; ++j)
        acc[i][j] = __builtin_amdgcn_mfma_scale_f32_16x16x128_f8f6f4(
            a[i], b0[j], acc[i][j], 0, 0, 0, 0x7F7F7F7F, 0, 0x7F7F7F7F);
    __builtin_amdgcn_s_setprio(0);
    __builtin_amdgcn_s_barrier();

    // ---- phase 1: read B-high frags; prefetch next B ----
#pragma unroll
    for (int j = 0; j < 2; ++j) b1[j] = ld_frag16(lB + offB[0][2 + j], lB + offB[1][2 + j]);
    if (pf) stageB(nb, k0n);
    __builtin_amdgcn_s_barrier();
    asm volatile("s_waitcnt lgkmcnt(0)" ::: "memory");
    __builtin_amdgcn_sched_barrier(0);
    __builtin_amdgcn_s_setprio(1);
#pragma unroll
    for (int i = 0; i < 4; ++i)
#pragma unroll
      for (int j = 0; j < 2; ++j)
        acc[i][2 + j] = __builtin_amdgcn_mfma_scale_f32_16x16x128_f8f6f4(
            a[i], b1[j], acc[i][2 + j], 0, 0, 0, 0x7F7F7F7F, 0, 0x7F7F7F7F);
    __builtin_amdgcn_s_setprio(0);
    __builtin_amdgcn_s_barrier();

    // ---- phase 2: read A-high frags (reuse b1) ----
#pragma unroll
    for (int i = 0; i < 4; ++i) a[i] = ld_frag16(lA + offA[0][4 + i], lA + offA[1][4 + i]);
    __builtin_amdgcn_s_barrier();
    asm volatile("s_waitcnt lgkmcnt(0)" ::: "memory");
    __builtin_amdgcn_sched_barrier(0);
    __builtin_amdgcn_s_setprio(1);
#pragma unroll
    for (int i = 0; i < 4; ++i)
#pragma unroll
      for (int j = 0; j < 2; ++j)
        acc[4 + i][2 + j] = __builtin_amdgcn_mfma_scale_f32_16x16x128_f8f6f4(
            a[i], b1[j], acc[4 + i][2 + j], 0, 0, 0, 0x7F7F7F7F, 0, 0x7F7F7F7F);
    __builtin_amdgcn_s_setprio(0);
    __builtin_amdgcn_s_barrier();

    // ---- phase 3: re-read B-low frags (reuse a = A-high); tile-boundary wait ----
#pragma unroll
    for (int j = 0; j < 2; ++j) b0[j] = ld_frag16(lB + offB[0][j], lB + offB[1][j]);
    __builtin_amdgcn_s_barrier();
    asm volatile("s_waitcnt lgkmcnt(0)" ::: "memory");
    __builtin_amdgcn_sched_barrier(0);
    __builtin_amdgcn_s_setprio(1);
#pragma unroll
    for (int i = 0; i < 4; ++i)
#pragma unroll
      for (int j = 0; j < 2; ++j)
        acc[4 + i][j] = __builtin_amdgcn_mfma_scale_f32_16x16x128_f8f6f4(
            a[i], b0[j], acc[4 + i][j], 0, 0, 0, 0x7F7F7F7F, 0, 0x7F7F7F7F);
    __builtin_amdgcn_s_setprio(0);
    asm volatile("s_waitcnt vmcnt(0)" ::: "memory");
    __builtin_amdgcn_s_barrier();
  }
}

// ---- V projection (bf16 128x128 core) + fused Vt8 transpose --------------------
__global__ __launch_bounds__(256, 2) void proj_v(
    const bf16* __restrict__ Xbf, const bf16* __restrict__ Wvbf, bf16* __restrict__ Vbf,
    unsigned char* __restrict__ Vt8) {
  __shared__ __align__(16) char lds[49152];
  const int id = blockIdx.x;
  const int tid = threadIdx.x, w = tid >> 6, lane = tid & 63;
  const int fr = lane & 15, fq = lane >> 4;

  const int r = id & 7, g = id >> 3;
  const int ty = r * 8 + (g & 7), tx = g >> 3;
  bf16* lA = (bf16*)lds;
  bf16* lB = (bf16*)(lds + 16384);
  floatx4 acc[4][4];
  gemm_core(Xbf + (size_t)ty * 128 * 1024, Wvbf + (size_t)tx * 128 * 1024,
            1024, lA, lB, acc);
  const int subM = (w >> 1) * 64, subN = (w & 1) * 64;
  const int rowBase = ty * 128 + subM;
  const int colBase = tx * 128 + subN;
#pragma unroll
  for (int i = 0; i < 4; ++i)
#pragma unroll
    for (int j = 0; j < 4; ++j)
#pragma unroll
      for (int rr = 0; rr < 4; ++rr) {
        int row = rowBase + i * 16 + fq * 4 + rr;
        int col = colBase + j * 16 + fr;
        Vbf[(size_t)row * 1024 + col] = __float2bfloat16(acc[i][j][rr]);
      }

  // fused V transpose: acc (f32) -> fp8 -> Vt8[b][v][pi(s)] via swizzled LDS
  __syncthreads();
  unsigned int* tp = (unsigned int*)lds;  // [128 v][32 s-words], XOR-swizzled
#pragma unroll
  for (int i = 0; i < 4; ++i) {
    int rw = (subM + i * 16 + fq * 4) >> 2;
#pragma unroll
    for (int j = 0; j < 4; ++j) {
      int c = subN + j * 16 + fr;
      tp[c * 32 + (rw ^ (c & 31))] =
          (unsigned int)pk4_fp8(acc[i][j][0], acc[i][j][1], acc[i][j][2], acc[i][j][3]);
    }
  }
  __syncthreads();
  const int vrow = tid >> 1;
  const int gh = tid & 1;
  size_t ob = ((size_t)((ty >> 4) * 1024 + tx * 128 + vrow)) * 2048 +
              (size_t)(ty & 15) * 128 + gh * 64;
#pragma unroll
  for (int h = 0; h < 4; ++h) {
    unsigned int W0 = tp[vrow * 32 + ((gh * 16 + h) ^ (vrow & 31))];
    unsigned int W1 = tp[vrow * 32 + ((gh * 16 + h + 4) ^ (vrow & 31))];
    unsigned int W2 = tp[vrow * 32 + ((gh * 16 + h + 8) ^ (vrow & 31))];
    unsigned int W3 = tp[vrow * 32 + ((gh * 16 + h + 12) ^ (vrow & 31))];
    unsigned int t01l = __builtin_amdgcn_perm(W1, W0, 0x05010400u);
    unsigned int t01h = __builtin_amdgcn_perm(W1, W0, 0x07030602u);
    unsigned int t23l = __builtin_amdgcn_perm(W3, W2, 0x05010400u);
    unsigned int t23h = __builtin_amdgcn_perm(W3, W2, 0x07030602u);
    uint4 o;
    o.x = __builtin_amdgcn_perm(t23l, t01l, 0x05040100u);
    o.y = __builtin_amdgcn_perm(t23l, t01l, 0x07060302u);
    o.z = __builtin_amdgcn_perm(t23h, t01h, 0x05040100u);
    o.w = __builtin_amdgcn_perm(t23h, t01h, 0x07060302u);
    *(uint4*)&Vt8[ob + h * 16] = o;
  }
}

// ---- Q/K projections, fp8 8-phase core (256x256), pi-permuted output (k=d) ----
__global__ __launch_bounds__(512, 2) void proj_qk(
    const unsigned char* __restrict__ X8, const unsigned char* __restrict__ Wq8,
    const unsigned char* __restrict__ Wk8,
    unsigned char* __restrict__ Qf8, unsigned char* __restrict__ Kf8) {
  __shared__ __align__(16) char lds[131072];
  const int id = blockIdx.x;             // 256 blocks: z(2) x ty(32) x tx(4)
  const int z = id >> 7, lid = id & 127;
  const int ty = lid >> 2, tx = lid & 3;

  floatx4 acc[8][4];
  gemm_core_f8_8ph(X8 + (size_t)ty * 256 * 1024,
                   (z == 0 ? Wq8 : Wk8) + (size_t)tx * 256 * 1024,
                   1024, (unsigned char*)lds, acc);

  unsigned char* dst = (z == 0) ? Qf8 : Kf8;
  const int tid = threadIdx.x, w = tid >> 6, lane = tid & 63;
  const int wr = w >> 2, wc = w & 3;
  const int fr = lane & 15, fq = lane >> 4;
  const int rowBase = ty * 256 + wr * 128;
  const int colBase = tx * 256 + wc * 64;
#pragma unroll
  for (int i = 0; i < 8; ++i)
#pragma unroll
    for (int rr = 0; rr < 4; ++rr) {
      int row = rowBase + i * 16 + fq * 4 + rr;
      unsigned int p0 = (unsigned int)pk4_fp8(acc[i][0][rr], acc[i][1][rr],
                                              acc[i][2][rr], acc[i][3][rr]);
      *(unsigned int*)&dst[(size_t)row * 1024 + colBase + fr * 4] = p0;
    }
}

// ---- QK^T + exp (fp8 8-phase core), pi-permuted output (k=s) ----
__global__ __launch_bounds__(512, 2) void mid_kernel(
    const unsigned char* __restrict__ Qf8, const unsigned char* __restrict__ Kf8,
    unsigned char* __restrict__ S8, float* __restrict__ l) {
  __shared__ __align__(16) char lds[131072];
  const int id = blockIdx.x;             // 256 blocks: b(4) x ty(8) x tx(8); id%8=tx
  const int b = id >> 6, ty = (id >> 3) & 7, tx = id & 7;

  floatx4 acc[8][4];
  gemm_core_f8_8ph(Qf8 + (size_t)b * 2048 * 1024 + (size_t)ty * 256 * 1024,
                   Kf8 + (size_t)b * 2048 * 1024 + (size_t)tx * 256 * 1024,
                   1024, (unsigned char*)lds, acc);

  const int tid = threadIdx.x, w = tid >> 6, lane = tid & 63;
  const int wr = w >> 2, wc = w & 3;
  const int fr = lane & 15, fq = lane >> 4;
  const int rowBase = ty * 256 + wr * 128;
  const int colBase = tx * 256 + wc * 64;
  unsigned char* Sb = S8 + (size_t)b * 2048 * 2048;
  float* lb = l + (size_t)b * 2048;
#pragma unroll
  for (int i = 0; i < 8; ++i)
#pragma unroll
    for (int rr = 0; rr < 4; ++rr) {
      int row = rowBase + i * 16 + fq * 4 + rr;
      unsigned int p0 = (unsigned int)pk4_fp8(
          __expf(acc[i][0][rr] * 0.03125f), __expf(acc[i][1][rr] * 0.03125f),
          __expf(acc[i][2][rr] * 0.03125f), __expf(acc[i][3][rr] * 0.03125f));
      *(unsigned int*)&Sb[(size_t)row * 2048 + colBase + fr * 4] = p0;
      float psum = __builtin_amdgcn_cvt_f32_fp8(p0, 0) + __builtin_amdgcn_cvt_f32_fp8(p0, 1) +
                   __builtin_amdgcn_cvt_f32_fp8(p0, 2) + __builtin_amdgcn_cvt_f32_fp8(p0, 3);
      psum += __shfl_xor(psum, 1, 64);
      psum += __shfl_xor(psum, 2, 64);
      psum += __shfl_xor(psum, 4, 64);
      psum += __shfl_xor(psum, 8, 64);
      if (fr == 0) atomicAdd(&lb[row], psum);
    }
}

// ---- PV (fp8 128x128 core) + normalize + residual: out = (E * Vt^T)/l + V ----
__global__ __launch_bounds__(256, 2) void pv_gemm(const unsigned char* __restrict__ S8,
                                                  const unsigned char* __restrict__ Vt8,
                                                  const bf16* __restrict__ Vbf,
                                                  const float* __restrict__ l,
                                                  float* __restrict__ out) {
  __shared__ __align__(16) char lds[32768];
  unsigned char* lA = (unsigned char*)lds;
  unsigned char* lB = (unsigned char*)(lds + 16384);
  const int id = blockIdx.x;
  const int r = id & 7, g = id >> 3;
  const int b = g >> 4;
  const int rem = g & 15;
  const int ty = r * 2 + (rem & 1);
  const int tx = rem >> 1;

  floatx4 acc[4][4];
  gemm_core_f8(S8 + (size_t)b * 2048 * 2048 + (size_t)ty * 128 * 2048,
               Vt8 + (size_t)b * 1024 * 2048 + (size_t)tx * 128 * 2048,
               2048, lA, lB, acc);

  const int tid = threadIdx.x, w = tid >> 6, lane = tid & 63;
  const int subM = (w >> 1) * 64, subN = (w & 1) * 64;
  const int fr = lane & 15, fq = lane >> 4;
  const int rowBase = ty * 128 + subM;
  const int colBase = tx * 128 + subN;
  const float* lb = l + (size_t)b * 2048;
#pragma unroll
  for (int i = 0; i < 4; ++i)
#pragma unroll
    for (int rr = 0; rr < 4; ++rr) {
      int row = rowBase + i * 16 + fq * 4 + rr;
      float inv = 1.0f / lb[row];
#pragma unroll
      for (int j = 0; j < 4; ++j) {
        int col = colBase + j * 16 + fr;
        size_t oi = ((size_t)b * 2048 + row) * 1024 + col;
        out[oi] = acc[i][j][rr] * inv + __bfloat162float(Vbf[oi]);
      }
    }
}

// ---- casts: x -> Xbf+X8; wq,wk -> fp8; wv -> bf16; zero l (4 float4/thread) ----
__global__ void cast_all(const float* __restrict__ x, const float* __restrict__ wq,
                         const float* __restrict__ wk, const float* __restrict__ wv,
                         bf16* __restrict__ Xbf, unsigned char* __restrict__ X8,
                         unsigned char* __restrict__ Wq8, unsigned char* __restrict__ Wk8,
                         bf16* __restrict__ Wvbf, float* __restrict__ l) {
  const int blk = blockIdx.x;
  const int t = threadIdx.x;
  if (blk < 2048) {  // x: bf16 + fp8 (2M float4 total)
#pragma unroll
    for (int k = 0; k < 4; ++k) {
      int i = blk * 1024 + k * 256 + t;
      float4 f = ((const float4*)x)[i];
      bf16 tmp[4] = {__float2bfloat16(f.x), __float2bfloat16(f.y),
                     __float2bfloat16(f.z), __float2bfloat16(f.w)};
      ((ushort4*)Xbf)[i] = *(const ushort4*)tmp;
      ((unsigned int*)X8)[i] = (unsigned int)pk4_fp8(f.x, f.y, f.z, f.w);
    }
  } else if (blk < 2560) {  // wq, wk: fp8 only (256 blocks each)
    const float* src = (blk < 2304) ? wq : wk;
    unsigned char* dst = (blk < 2304) ? Wq8 : Wk8;
    int base = ((blk - 2048) & 255) * 1024;
#pragma unroll
    for (int k = 0; k < 4; ++k) {
      int i = base + k * 256 + t;
      float4 f = ((const float4*)src)[i];
      ((unsigned int*)dst)[i] = (unsigned int)pk4_fp8(f.x, f.y, f.z, f.w);
    }
  } else if (blk < 2816) {  // wv: bf16 only (256 blocks)
#pragma unroll
    for (int k = 0; k < 4; ++k) {
      int i = (blk - 2560) * 1024 + k * 256 + t;
      float4 f = ((const float4*)wv)[i];
      bf16 tmp[4] = {__float2bfloat16(f.x), __float2bfloat16(f.y),
                     __float2bfloat16(f.z), __float2bfloat16(f.w)};
      ((ushort4*)Wvbf)[i] = *(const ushort4*)tmp;
    }
  } else {  // zero l (8192 floats)
#pragma unroll
    for (int k = 0; k < 8; ++k)
      ((float4*)l)[k * 256 + t] = make_float4(0.f, 0.f, 0.f, 0.f);
  }
}

extern "C" void kernel_launch(void* const* d_in, const int* in_sizes, int n_in,
                              void* d_out, int out_size, void* d_ws, size_t ws_size,
                              hipStream_t stream) {
  const float* x  = (const float*)d_in[0];
  const float* Wq = (const float*)d_in[1];
  const float* Wk = (const float*)d_in[2];
  const float* Wv = (const float*)d_in[3];
  float* out = (float*)d_out;

  char* ws = (char*)d_ws;
  bf16* Xbf = (bf16*)ws;                   ws += (size_t)8192 * 1024 * 2;   // 16 MB
  unsigned char* X8 = (unsigned char*)ws;  ws += (size_t)8192 * 1024;       // 8 MB
  unsigned char* Wq8 = (unsigned char*)ws; ws += (size_t)1024 * 1024;       // 1 MB
  unsigned char* Wk8 = (unsigned char*)ws; ws += (size_t)1024 * 1024;       // 1 MB
  bf16* Wvbf = (bf16*)ws;                  ws += (size_t)1024 * 1024 * 2;   // 2 MB
  unsigned char* Qf8 = (unsigned char*)ws; ws += (size_t)8192 * 1024;       // 8 MB
  unsigned char* Kf8 = (unsigned char*)ws; ws += (size_t)8192 * 1024;       // 8 MB
  bf16* Vbf = (bf16*)ws;                   ws += (size_t)8192 * 1024 * 2;   // 16 MB
  unsigned char* Vt8 = (unsigned char*)ws; ws += (size_t)4 * 1024 * 2048;   // 8 MB
  unsigned char* S8  = (unsigned char*)ws; ws += (size_t)4 * 2048 * 2048;   // 16 MB
  float* l = (float*)ws;                   ws += (size_t)8192 * 4;

  cast_all<<<2817, 256, 0, stream>>>(x, Wq, Wk, Wv, Xbf, X8, Wq8, Wk8, Wvbf, l);
  proj_v<<<512, 256, 0, stream>>>(Xbf, Wvbf, Vbf, Vt8);
  proj_qk<<<256, 512, 0, stream>>>(X8, Wq8, Wk8, Qf8, Kf8);
  mid_kernel<<<256, 512, 0, stream>>>(Qf8, Kf8, S8, l);
  pv_gemm<<<512, 256, 0, stream>>>(S8, Vt8, Vbf, l, out);
}

// Round 3
// 187.158 us; speedup vs baseline: 1.0048x; 1.0048x over previous
//
#include <hip/hip_runtime.h>
#include <hip/hip_bf16.h>

using bf16 = __hip_bfloat16;
typedef __attribute__((ext_vector_type(8))) short short8;   // 8 bf16 = 4 VGPRs
typedef __attribute__((ext_vector_type(4))) float floatx4;  // 4 fp32 acc
typedef __attribute__((ext_vector_type(8))) int int8v;      // 32 fp8 = 8 VGPRs

__device__ __forceinline__ void async_ld16(const void* g, void* l) {
  __builtin_amdgcn_global_load_lds((const __attribute__((address_space(1))) void*)g,
                                   (__attribute__((address_space(3))) void*)l, 16, 0, 0);
}

__device__ __forceinline__ int pk4_fp8(float a, float b, float c, float d) {
  int v = __builtin_amdgcn_cvt_pk_fp8_f32(a, b, 0, false);
  return __builtin_amdgcn_cvt_pk_fp8_f32(c, d, v, true);  // bytes [a,b,c,d]
}

__device__ __forceinline__ int8v ld_frag16(const unsigned char* lo, const unsigned char* hi) {
  int4 l0 = *(const int4*)lo, h0 = *(const int4*)hi;
  int8v v;
  v[0] = l0.x; v[1] = l0.y; v[2] = l0.z; v[3] = l0.w;
  v[4] = h0.x; v[5] = h0.y; v[6] = h0.z; v[7] = h0.w;
  return v;
}

// Swizzle: chunk j of row r stored at position j ^ (r&7) ^ ((r&8)>>1).
// The r&8 term puts rows fr and fr+8 (same 16-lane read phase) 16 banks apart.

// ---------------- bf16 128x128 tile core (BK=64) — unchanged (0 conflicts) ----------
__device__ __forceinline__ void gemm_core(const bf16* __restrict__ At,
                                          const bf16* __restrict__ Bt,
                                          int K, bf16* lA, bf16* lB,
                                          floatx4 acc[4][4]) {
  const int tid  = threadIdx.x;
  const int w    = tid >> 6;
  const int lane = tid & 63;
  const int subM = (w >> 1) * 64;
  const int subN = (w & 1) * 64;
  const int fr   = lane & 15;
  const int fq   = lane >> 4;

  int srow[4], scol[4], sdst[4];
#pragma unroll
  for (int q = 0; q < 4; ++q) {
    int p = q * 256 + w * 64 + lane;
    int r = p >> 3;
    int j = (p & 7) ^ (r & 7);
    srow[q] = r;
    scol[q] = j * 8;
    sdst[q] = (q * 256 + w * 64) * 8;
  }
  int offA[2][4], offB[2][4];
#pragma unroll
  for (int kc = 0; kc < 2; ++kc)
#pragma unroll
    for (int i = 0; i < 4; ++i) {
      int rA = subM + i * 16 + fr;
      offA[kc][i] = (rA * 8 + ((kc * 4 + fq) ^ (rA & 7))) * 8;
      int rB = subN + i * 16 + fr;
      offB[kc][i] = (rB * 8 + ((kc * 4 + fq) ^ (rB & 7))) * 8;
    }

  floatx4 zero = {0.f, 0.f, 0.f, 0.f};
#pragma unroll
  for (int i = 0; i < 4; ++i)
#pragma unroll
    for (int j = 0; j < 4; ++j) acc[i][j] = zero;

  for (int k0 = 0; k0 < K; k0 += 64) {
    __syncthreads();
#pragma unroll
    for (int q = 0; q < 4; ++q) {
      async_ld16(At + (size_t)srow[q] * K + k0 + scol[q], lA + sdst[q]);
      async_ld16(Bt + (size_t)srow[q] * K + k0 + scol[q], lB + sdst[q]);
    }
    __syncthreads();
#pragma unroll
    for (int kc = 0; kc < 2; ++kc) {
      short8 a[4], b[4];
#pragma unroll
      for (int i = 0; i < 4; ++i) a[i] = *(const short8*)(lA + offA[kc][i]);
#pragma unroll
      for (int j = 0; j < 4; ++j) b[j] = *(const short8*)(lB + offB[kc][j]);
#pragma unroll
      for (int i = 0; i < 4; ++i)
#pragma unroll
        for (int j = 0; j < 4; ++j)
          acc[i][j] = __builtin_amdgcn_mfma_f32_16x16x32_bf16(a[i], b[j], acc[i][j], 0, 0, 0);
    }
  }
}

// ---------------- fp8 128x128 tile core (BK=128) — used by pv ---------------------
__device__ __forceinline__ void gemm_core_f8(const unsigned char* __restrict__ At,
                                             const unsigned char* __restrict__ Bt,
                                             int K, unsigned char* lA, unsigned char* lB,
                                             floatx4 acc[4][4]) {
  const int tid  = threadIdx.x;
  const int w    = tid >> 6;
  const int lane = tid & 63;
  const int subM = (w >> 1) * 64;
  const int subN = (w & 1) * 64;
  const int fr   = lane & 15;
  const int fq   = lane >> 4;

  int srow[4], scol[4], sdst[4];
#pragma unroll
  for (int q = 0; q < 4; ++q) {
    int p = q * 256 + w * 64 + lane;
    int r = p >> 3;
    int j = (p & 7) ^ (r & 7) ^ ((r & 8) >> 1);
    srow[q] = r;
    scol[q] = j * 16;
    sdst[q] = (q * 256 + w * 64) * 16;
  }
  int offA[2][4], offB[2][4];
#pragma unroll
  for (int h = 0; h < 2; ++h)
#pragma unroll
    for (int i = 0; i < 4; ++i) {
      int rA = subM + i * 16 + fr;
      offA[h][i] = rA * 128 + (((fq * 2 + h) ^ (rA & 7) ^ ((rA & 8) >> 1)) * 16);
      int rB = subN + i * 16 + fr;
      offB[h][i] = rB * 128 + (((fq * 2 + h) ^ (rB & 7) ^ ((rB & 8) >> 1)) * 16);
    }

  floatx4 zero = {0.f, 0.f, 0.f, 0.f};
#pragma unroll
  for (int i = 0; i < 4; ++i)
#pragma unroll
    for (int j = 0; j < 4; ++j) acc[i][j] = zero;

  for (int k0 = 0; k0 < K; k0 += 128) {
    __syncthreads();
#pragma unroll
    for (int q = 0; q < 4; ++q) {
      async_ld16(At + (size_t)srow[q] * K + k0 + scol[q], lA + sdst[q]);
      async_ld16(Bt + (size_t)srow[q] * K + k0 + scol[q], lB + sdst[q]);
    }
    __syncthreads();
    int8v a[4], b[4];
#pragma unroll
    for (int i = 0; i < 4; ++i) a[i] = ld_frag16(lA + offA[0][i], lA + offA[1][i]);
#pragma unroll
    for (int j = 0; j < 4; ++j) b[j] = ld_frag16(lB + offB[0][j], lB + offB[1][j]);
#pragma unroll
    for (int i = 0; i < 4; ++i)
#pragma unroll
      for (int j = 0; j < 4; ++j)
        acc[i][j] = __builtin_amdgcn_mfma_scale_f32_16x16x128_f8f6f4(
            a[i], b[j], acc[i][j], 0, 0, 0, 0x7F7F7F7F, 0, 0x7F7F7F7F);
  }
}

// ============ fp8 8-phase core v2: block 256x256, 8 waves (2Mx4N), BK=128 ==========
// Stage segments congruent with phase consumption (each 128 rows = 2 loads/thread):
//   SA0 = A rows {0-63, 128-191}   (read by phase 0: both wr waves' frags i=0..3)
//   SA1 = A rows {64-127, 192-255} (read by phase 2)
//   SB0 = B rows {wc*64+[0,32)}    (read by phases 0,3: frags j=0..1, all wc)
//   SB1 = B rows {wc*64+[32,64)}   (read by phase 1)
// Per tile t: P0 issues {SA0,SB0}(t+1); P1 issues {SA1,SB1}(t+1).
// Waits: vmcnt(4) at P0-end (drains {SA1,SB1}(t), needed by P1/P2) and at P3-end
// (drains {SA0,SB0}(t+1), needed by next P0). Never drains to 0; each load has
// ~3.5 phases (>1500 cy) of cover. Waits precede a barrier so per-wave drain
// becomes a block-wide guarantee. Tail prefetch wraps to keep counts uniform.
__device__ __forceinline__ void gemm_core_f8_8ph(const unsigned char* __restrict__ At,
                                                 const unsigned char* __restrict__ Bt,
                                                 int K, unsigned char* lds0,
                                                 floatx4 acc[8][4]) {
  const int tid  = threadIdx.x;
  const int w    = tid >> 6;
  const int lane = tid & 63;
  const int wr   = w >> 2;
  const int wc   = w & 3;
  const int subM = wr * 128;
  const int subN = wc * 64;
  const int fr   = lane & 15;
  const int fq   = lane >> 4;

  // srcOff/dstOff for 4 segments x 2 loads each
  int srcOff[4][2], dstOff[4][2];
#pragma unroll
  for (int s = 0; s < 4; ++s)
#pragma unroll
    for (int ldi = 0; ldi < 2; ++ldi) {
      int c = ldi * 512 + tid;       // chunk within segment [0,1024)
      int rs = c >> 3;               // row-within-segment [0,128)
      int row;
      if (s == 0)      row = (rs < 64) ? rs : rs + 64;          // SA0
      else if (s == 2) row = 64 + ((rs < 64) ? rs : rs + 64);   // SA1
      else if (s == 1) row = (rs & 31) + (rs >> 5) * 64;        // SB0
      else             row = 32 + (rs & 31) + (rs >> 5) * 64;   // SB1
      int j = (c & 7) ^ (row & 7) ^ ((row & 8) >> 1);
      srcOff[s][ldi] = row * K + j * 16;
      dstOff[s][ldi] = row * 128 + (c & 7) * 16;
    }

  int offA[2][8], offB[2][4];
#pragma unroll
  for (int h = 0; h < 2; ++h) {
#pragma unroll
    for (int i = 0; i < 8; ++i) {
      int rA = subM + i * 16 + fr;
      offA[h][i] = rA * 128 + (((fq * 2 + h) ^ (rA & 7) ^ ((rA & 8) >> 1)) * 16);
    }
#pragma unroll
    for (int j = 0; j < 4; ++j) {
      int rB = subN + j * 16 + fr;
      offB[h][j] = rB * 128 + (((fq * 2 + h) ^ (rB & 7) ^ ((rB & 8) >> 1)) * 16);
    }
  }

  auto stage = [&](int buf, int k0, int s) {
    const unsigned char* src = (s & 1) ? Bt : At;
    unsigned char* dstb = lds0 + buf * 65536 + ((s & 1) ? 32768 : 0);
    async_ld16(src + (size_t)(k0 + srcOff[s][0]), dstb + dstOff[s][0]);
    async_ld16(src + (size_t)(k0 + srcOff[s][1]), dstb + dstOff[s][1]);
  };

  floatx4 zero = {0.f, 0.f, 0.f, 0.f};
#pragma unroll
  for (int i = 0; i < 8; ++i)
#pragma unroll
    for (int j = 0; j < 4; ++j) acc[i][j] = zero;

  const int nt = K >> 7;
  // prologue: stage tile 0 in steady-state issue order; drain SA0,SB0 only
  stage(0, 0, 0);  // SA0
  stage(0, 0, 1);  // SB0
  stage(0, 0, 2);  // SA1
  stage(0, 0, 3);  // SB1
  asm volatile("s_waitcnt vmcnt(4)" ::: "memory");
  __builtin_amdgcn_s_barrier();

  for (int t = 0; t < nt; ++t) {
    const unsigned char* lA = lds0 + (t & 1) * 65536;
    const unsigned char* lB = lA + 32768;
    const int nb = (t + 1) & 1;
    const int tn = (t + 1 < nt) ? (t + 1) : 0;   // wrap tail prefetch (harmless)
    const int k0n = tn << 7;
    int8v a[4], b0[2], b1[2];

    // ---- phase 0: read A-frags i0-3 + B-frags j0-1; issue {SA0,SB0}(t+1) ----
#pragma unroll
    for (int i = 0; i < 4; ++i) a[i] = ld_frag16(lA + offA[0][i], lA + offA[1][i]);
#pragma unroll
    for (int j = 0; j < 2; ++j) b0[j] = ld_frag16(lB + offB[0][j], lB + offB[1][j]);
    stage(nb, k0n, 0);
    stage(nb, k0n, 1);
    __builtin_amdgcn_s_barrier();
    asm volatile("s_waitcnt lgkmcnt(0)" ::: "memory");
    __builtin_amdgcn_sched_barrier(0);
    __builtin_amdgcn_s_setprio(1);
#pragma unroll
    for (int i = 0; i < 4; ++i)
#pragma unroll
      for (int j = 0; j < 2; ++j)
        acc[i][j] = __builtin_amdgcn_mfma_scale_f32_16x16x128_f8f6f4(
            a[i], b0[j], acc[i][j], 0, 0, 0, 0x7F7F7F7F, 0, 0x7F7F7F7F);
    __builtin_amdgcn_s_setprio(0);
    asm volatile("s_waitcnt vmcnt(4)" ::: "memory");  // {SA1,SB1}(t) done
    __builtin_amdgcn_s_barrier();

    // ---- phase 1: read B-frags j2-3; issue {SA1,SB1}(t+1) ----
#pragma unroll
    for (int j = 0; j < 2; ++j) b1[j] = ld_frag16(lB + offB[0][2 + j], lB + offB[1][2 + j]);
    stage(nb, k0n, 2);
    stage(nb, k0n, 3);
    __builtin_amdgcn_s_barrier();
    asm volatile("s_waitcnt lgkmcnt(0)" ::: "memory");
    __builtin_amdgcn_sched_barrier(0);
    __builtin_amdgcn_s_setprio(1);
#pragma unroll
    for (int i = 0; i < 4; ++i)
#pragma unroll
      for (int j = 0; j < 2; ++j)
        acc[i][2 + j] = __builtin_amdgcn_mfma_scale_f32_16x16x128_f8f6f4(
            a[i], b1[j], acc[i][2 + j], 0, 0, 0, 0x7F7F7F7F, 0, 0x7F7F7F7F);
    __builtin_amdgcn_s_setprio(0);
    __builtin_amdgcn_s_barrier();

    // ---- phase 2: read A-frags i4-7 (reuse b1) ----
#pragma unroll
    for (int i = 0; i < 4; ++i) a[i] = ld_frag16(lA + offA[0][4 + i], lA + offA[1][4 + i]);
    __builtin_amdgcn_s_barrier();
    asm volatile("s_waitcnt lgkmcnt(0)" ::: "memory");
    __builtin_amdgcn_sched_barrier(0);
    __builtin_amdgcn_s_setprio(1);
#pragma unroll
    for (int i = 0; i < 4; ++i)
#pragma unroll
      for (int j = 0; j < 2; ++j)
        acc[4 + i][2 + j] = __builtin_amdgcn_mfma_scale_f32_16x16x128_f8f6f4(
            a[i], b1[j], acc[4 + i][2 + j], 0, 0, 0, 0x7F7F7F7F, 0, 0x7F7F7F7F);
    __builtin_amdgcn_s_setprio(0);
    __builtin_amdgcn_s_barrier();

    // ---- phase 3: re-read B-frags j0-1 (reuse a = A-hi); boundary wait ----
#pragma unroll
    for (int j = 0; j < 2; ++j) b0[j] = ld_frag16(lB + offB[0][j], lB + offB[1][j]);
    __builtin_amdgcn_s_barrier();
    asm volatile("s_waitcnt lgkmcnt(0)" ::: "memory");
    __builtin_amdgcn_sched_barrier(0);
    __builtin_amdgcn_s_setprio(1);
#pragma unroll
    for (int i = 0; i < 4; ++i)
#pragma unroll
      for (int j = 0; j < 2; ++j)
        acc[4 + i][j] = __builtin_amdgcn_mfma_scale_f32_16x16x128_f8f6f4(
            a[i], b0[j], acc[4 + i][j], 0, 0, 0, 0x7F7F7F7F, 0, 0x7F7F7F7F);
    __builtin_amdgcn_s_setprio(0);
    asm volatile("s_waitcnt vmcnt(4)" ::: "memory");  // {SA0,SB0}(t+1) done
    __builtin_amdgcn_s_barrier();
  }
  asm volatile("s_waitcnt vmcnt(0)" ::: "memory");  // hygiene before epilogue
}

// ---- V projection (bf16 128x128 core) + fused Vt8 transpose --------------------
__global__ __launch_bounds__(256, 2) void proj_v(
    const bf16* __restrict__ Xbf, const bf16* __restrict__ Wvbf, bf16* __restrict__ Vbf,
    unsigned char* __restrict__ Vt8) {
  __shared__ __align__(16) char lds[49152];
  const int id = blockIdx.x;
  const int tid = threadIdx.x, w = tid >> 6, lane = tid & 63;
  const int fr = lane & 15, fq = lane >> 4;

  const int r = id & 7, g = id >> 3;
  const int ty = r * 8 + (g & 7), tx = g >> 3;
  bf16* lA = (bf16*)lds;
  bf16* lB = (bf16*)(lds + 16384);
  floatx4 acc[4][4];
  gemm_core(Xbf + (size_t)ty * 128 * 1024, Wvbf + (size_t)tx * 128 * 1024,
            1024, lA, lB, acc);
  const int subM = (w >> 1) * 64, subN = (w & 1) * 64;
  const int rowBase = ty * 128 + subM;
  const int colBase = tx * 128 + subN;
#pragma unroll
  for (int i = 0; i < 4; ++i)
#pragma unroll
    for (int j = 0; j < 4; ++j)
#pragma unroll
      for (int rr = 0; rr < 4; ++rr) {
        int row = rowBase + i * 16 + fq * 4 + rr;
        int col = colBase + j * 16 + fr;
        Vbf[(size_t)row * 1024 + col] = __float2bfloat16(acc[i][j][rr]);
      }

  // fused V transpose: acc (f32) -> fp8 -> Vt8[b][v][pi(s)] via swizzled LDS
  __syncthreads();
  unsigned int* tp = (unsigned int*)lds;  // [128 v][32 s-words], XOR-swizzled
#pragma unroll
  for (int i = 0; i < 4; ++i) {
    int rw = (subM + i * 16 + fq * 4) >> 2;
#pragma unroll
    for (int j = 0; j < 4; ++j) {
      int c = subN + j * 16 + fr;
      tp[c * 32 + (rw ^ (c & 31))] =
          (unsigned int)pk4_fp8(acc[i][j][0], acc[i][j][1], acc[i][j][2], acc[i][j][3]);
    }
  }
  __syncthreads();
  const int vrow = tid >> 1;
  const int gh = tid & 1;
  size_t ob = ((size_t)((ty >> 4) * 1024 + tx * 128 + vrow)) * 2048 +
              (size_t)(ty & 15) * 128 + gh * 64;
#pragma unroll
  for (int h = 0; h < 4; ++h) {
    unsigned int W0 = tp[vrow * 32 + ((gh * 16 + h) ^ (vrow & 31))];
    unsigned int W1 = tp[vrow * 32 + ((gh * 16 + h + 4) ^ (vrow & 31))];
    unsigned int W2 = tp[vrow * 32 + ((gh * 16 + h + 8) ^ (vrow & 31))];
    unsigned int W3 = tp[vrow * 32 + ((gh * 16 + h + 12) ^ (vrow & 31))];
    unsigned int t01l = __builtin_amdgcn_perm(W1, W0, 0x05010400u);
    unsigned int t01h = __builtin_amdgcn_perm(W1, W0, 0x07030602u);
    unsigned int t23l = __builtin_amdgcn_perm(W3, W2, 0x05010400u);
    unsigned int t23h = __builtin_amdgcn_perm(W3, W2, 0x07030602u);
    uint4 o;
    o.x = __builtin_amdgcn_perm(t23l, t01l, 0x05040100u);
    o.y = __builtin_amdgcn_perm(t23l, t01l, 0x07060302u);
    o.z = __builtin_amdgcn_perm(t23h, t01h, 0x05040100u);
    o.w = __builtin_amdgcn_perm(t23h, t01h, 0x07060302u);
    *(uint4*)&Vt8[ob + h * 16] = o;
  }
}

// ---- Q/K projections, fp8 8-phase core (256x256), pi-permuted output (k=d) ----
__global__ __launch_bounds__(512, 2) void proj_qk(
    const unsigned char* __restrict__ X8, const unsigned char* __restrict__ Wq8,
    const unsigned char* __restrict__ Wk8,
    unsigned char* __restrict__ Qf8, unsigned char* __restrict__ Kf8) {
  __shared__ __align__(16) char lds[131072];
  const int id = blockIdx.x;             // 256 blocks: z(2) x ty(32) x tx(4)
  const int z = id >> 7, lid = id & 127;
  const int ty = lid >> 2, tx = lid & 3;

  floatx4 acc[8][4];
  gemm_core_f8_8ph(X8 + (size_t)ty * 256 * 1024,
                   (z == 0 ? Wq8 : Wk8) + (size_t)tx * 256 * 1024,
                   1024, (unsigned char*)lds, acc);

  unsigned char* dst = (z == 0) ? Qf8 : Kf8;
  const int tid = threadIdx.x, w = tid >> 6, lane = tid & 63;
  const int wr = w >> 2, wc = w & 3;
  const int fr = lane & 15, fq = lane >> 4;
  const int rowBase = ty * 256 + wr * 128;
  const int colBase = tx * 256 + wc * 64;
#pragma unroll
  for (int i = 0; i < 8; ++i)
#pragma unroll
    for (int rr = 0; rr < 4; ++rr) {
      int row = rowBase + i * 16 + fq * 4 + rr;
      unsigned int p0 = (unsigned int)pk4_fp8(acc[i][0][rr], acc[i][1][rr],
                                              acc[i][2][rr], acc[i][3][rr]);
      *(unsigned int*)&dst[(size_t)row * 1024 + colBase + fr * 4] = p0;
    }
}

// ---- QK^T + exp (fp8 8-phase core), pi-permuted output (k=s) ----
__global__ __launch_bounds__(512, 2) void mid_kernel(
    const unsigned char* __restrict__ Qf8, const unsigned char* __restrict__ Kf8,
    unsigned char* __restrict__ S8, float* __restrict__ l) {
  __shared__ __align__(16) char lds[131072];
  const int id = blockIdx.x;             // 256 blocks: b(4) x ty(8) x tx(8); id%8=tx
  const int b = id >> 6, ty = (id >> 3) & 7, tx = id & 7;

  floatx4 acc[8][4];
  gemm_core_f8_8ph(Qf8 + (size_t)b * 2048 * 1024 + (size_t)ty * 256 * 1024,
                   Kf8 + (size_t)b * 2048 * 1024 + (size_t)tx * 256 * 1024,
                   1024, (unsigned char*)lds, acc);

  const int tid = threadIdx.x, w = tid >> 6, lane = tid & 63;
  const int wr = w >> 2, wc = w & 3;
  const int fr = lane & 15, fq = lane >> 4;
  const int rowBase = ty * 256 + wr * 128;
  const int colBase = tx * 256 + wc * 64;
  unsigned char* Sb = S8 + (size_t)b * 2048 * 2048;
  float* lb = l + (size_t)b * 2048;
#pragma unroll
  for (int i = 0; i < 8; ++i)
#pragma unroll
    for (int rr = 0; rr < 4; ++rr) {
      int row = rowBase + i * 16 + fq * 4 + rr;
      unsigned int p0 = (unsigned int)pk4_fp8(
          __expf(acc[i][0][rr] * 0.03125f), __expf(acc[i][1][rr] * 0.03125f),
          __expf(acc[i][2][rr] * 0.03125f), __expf(acc[i][3][rr] * 0.03125f));
      *(unsigned int*)&Sb[(size_t)row * 2048 + colBase + fr * 4] = p0;
      float psum = __builtin_amdgcn_cvt_f32_fp8(p0, 0) + __builtin_amdgcn_cvt_f32_fp8(p0, 1) +
                   __builtin_amdgcn_cvt_f32_fp8(p0, 2) + __builtin_amdgcn_cvt_f32_fp8(p0, 3);
      psum += __shfl_xor(psum, 1, 64);
      psum += __shfl_xor(psum, 2, 64);
      psum += __shfl_xor(psum, 4, 64);
      psum += __shfl_xor(psum, 8, 64);
      if (fr == 0) atomicAdd(&lb[row], psum);
    }
}

// ---- PV (fp8 128x128 core) + normalize + residual: out = (E * Vt^T)/l + V ----
__global__ __launch_bounds__(256, 2) void pv_gemm(const unsigned char* __restrict__ S8,
                                                  const unsigned char* __restrict__ Vt8,
                                                  const bf16* __restrict__ Vbf,
                                                  const float* __restrict__ l,
                                                  float* __restrict__ out) {
  __shared__ __align__(16) char lds[32768];
  unsigned char* lA = (unsigned char*)lds;
  unsigned char* lB = (unsigned char*)(lds + 16384);
  const int id = blockIdx.x;
  const int r = id & 7, g = id >> 3;
  const int b = g >> 4;
  const int rem = g & 15;
  const int ty = r * 2 + (rem & 1);
  const int tx = rem >> 1;

  floatx4 acc[4][4];
  gemm_core_f8(S8 + (size_t)b * 2048 * 2048 + (size_t)ty * 128 * 2048,
               Vt8 + (size_t)b * 1024 * 2048 + (size_t)tx * 128 * 2048,
               2048, lA, lB, acc);

  const int tid = threadIdx.x, w = tid >> 6, lane = tid & 63;
  const int subM = (w >> 1) * 64, subN = (w & 1) * 64;
  const int fr = lane & 15, fq = lane >> 4;
  const int rowBase = ty * 128 + subM;
  const int colBase = tx * 128 + subN;
  const float* lb = l + (size_t)b * 2048;
#pragma unroll
  for (int i = 0; i < 4; ++i)
#pragma unroll
    for (int rr = 0; rr < 4; ++rr) {
      int row = rowBase + i * 16 + fq * 4 + rr;
      float inv = 1.0f / lb[row];
#pragma unroll
      for (int j = 0; j < 4; ++j) {
        int col = colBase + j * 16 + fr;
        size_t oi = ((size_t)b * 2048 + row) * 1024 + col;
        out[oi] = acc[i][j][rr] * inv + __bfloat162float(Vbf[oi]);
      }
    }
}

// ---- casts: x -> Xbf+X8; wq,wk -> fp8; wv -> bf16; zero l (4 float4/thread) ----
__global__ void cast_all(const float* __restrict__ x, const float* __restrict__ wq,
                         const float* __restrict__ wk, const float* __restrict__ wv,
                         bf16* __restrict__ Xbf, unsigned char* __restrict__ X8,
                         unsigned char* __restrict__ Wq8, unsigned char* __restrict__ Wk8,
                         bf16* __restrict__ Wvbf, float* __restrict__ l) {
  const int blk = blockIdx.x;
  const int t = threadIdx.x;
  if (blk < 2048) {  // x: bf16 + fp8 (2M float4 total)
#pragma unroll
    for (int k = 0; k < 4; ++k) {
      int i = blk * 1024 + k * 256 + t;
      float4 f = ((const float4*)x)[i];
      bf16 tmp[4] = {__float2bfloat16(f.x), __float2bfloat16(f.y),
                     __float2bfloat16(f.z), __float2bfloat16(f.w)};
      ((ushort4*)Xbf)[i] = *(const ushort4*)tmp;
      ((unsigned int*)X8)[i] = (unsigned int)pk4_fp8(f.x, f.y, f.z, f.w);
    }
  } else if (blk < 2560) {  // wq, wk: fp8 only (256 blocks each)
    const float* src = (blk < 2304) ? wq : wk;
    unsigned char* dst = (blk < 2304) ? Wq8 : Wk8;
    int base = ((blk - 2048) & 255) * 1024;
#pragma unroll
    for (int k = 0; k < 4; ++k) {
      int i = base + k * 256 + t;
      float4 f = ((const float4*)src)[i];
      ((unsigned int*)dst)[i] = (unsigned int)pk4_fp8(f.x, f.y, f.z, f.w);
    }
  } else if (blk < 2816) {  // wv: bf16 only (256 blocks)
#pragma unroll
    for (int k = 0; k < 4; ++k) {
      int i = (blk - 2560) * 1024 + k * 256 + t;
      float4 f = ((const float4*)wv)[i];
      bf16 tmp[4] = {__float2bfloat16(f.x), __float2bfloat16(f.y),
                     __float2bfloat16(f.z), __float2bfloat16(f.w)};
      ((ushort4*)Wvbf)[i] = *(const ushort4*)tmp;
    }
  } else {  // zero l (8192 floats)
#pragma unroll
    for (int k = 0; k < 8; ++k)
      ((float4*)l)[k * 256 + t] = make_float4(0.f, 0.f, 0.f, 0.f);
  }
}

extern "C" void kernel_launch(void* const* d_in, const int* in_sizes, int n_in,
                              void* d_out, int out_size, void* d_ws, size_t ws_size,
                              hipStream_t stream) {
  const float* x  = (const float*)d_in[0];
  const float* Wq = (const float*)d_in[1];
  const float* Wk = (const float*)d_in[2];
  const float* Wv = (const float*)d_in[3];
  float* out = (float*)d_out;

  char* ws = (char*)d_ws;
  bf16* Xbf = (bf16*)ws;                   ws += (size_t)8192 * 1024 * 2;   // 16 MB
  unsigned char* X8 = (unsigned char*)ws;  ws += (size_t)8192 * 1024;       // 8 MB
  unsigned char* Wq8 = (unsigned char*)ws; ws += (size_t)1024 * 1024;       // 1 MB
  unsigned char* Wk8 = (unsigned char*)ws; ws += (size_t)1024 * 1024;       // 1 MB
  bf16* Wvbf = (bf16*)ws;                  ws += (size_t)1024 * 1024 * 2;   // 2 MB
  unsigned char* Qf8 = (unsigned char*)ws; ws += (size_t)8192 * 1024;       // 8 MB
  unsigned char* Kf8 = (unsigned char*)ws; ws += (size_t)8192 * 1024;       // 8 MB
  bf16* Vbf = (bf16*)ws;                   ws += (size_t)8192 * 1024 * 2;   // 16 MB
  unsigned char* Vt8 = (unsigned char*)ws; ws += (size_t)4 * 1024 * 2048;   // 8 MB
  unsigned char* S8  = (unsigned char*)ws; ws += (size_t)4 * 2048 * 2048;   // 16 MB
  float* l = (float*)ws;                   ws += (size_t)8192 * 4;

  cast_all<<<2817, 256, 0, stream>>>(x, Wq, Wk, Wv, Xbf, X8, Wq8, Wk8, Wvbf, l);
  proj_v<<<512, 256, 0, stream>>>(Xbf, Wvbf, Vbf, Vt8);
  proj_qk<<<256, 512, 0, stream>>>(X8, Wq8, Wk8, Qf8, Kf8);
  mid_kernel<<<256, 512, 0, stream>>>(Qf8, Kf8, S8, l);
  pv_gemm<<<512, 256, 0, stream>>>(S8, Vt8, Vbf, l, out);
}